// Round 8
// baseline (286.604 us; speedup 1.0000x reference)
//
#include <hip/hip_runtime.h>
#include <stdint.h>

#define BATCH 1024
#define DIM 768

typedef unsigned long long u64;
typedef __attribute__((ext_vector_type(8))) short short8;  // 8 bf16 = 4 VGPRs
typedef __attribute__((ext_vector_type(4))) float f32x4;

// Workspace layout (bytes):
//   [0]      u64   hashes[1024]        (8 KB)
//   [8192]   float acc
//   [8196]   int   counter             (finalizer count, 0..64)
//   [8200]   int   rgc[64]             (per-row-group chunk arrivals)
//   [12288]  float pmax[1024*4]
//   [28672]  float psum[1024*4]
//   [49152]  ushort txtB[1024*768]     (1.5 MB) bf16, MFMA B-frag order
// B-frag order: off(col,k) = ((k>>5)*64 + (col>>4))*512 + ((k>>3)&3)*128
//                            + (col&15)*8 + (k&7)
// -> a wave's 16x16x32 B-fragment is one contiguous 1 KB run (16 B/lane).
#define WS_ACC  8192
#define WS_RGC  8200
#define WS_PMAX 12288
#define WS_PSUM 28672
#define WS_TXTB 49152

__device__ __forceinline__ unsigned short to_bf16(float x) {
    unsigned int u = __float_as_uint(x);
    return (unsigned short)((u + 0x7FFFu + ((u >> 16) & 1u)) >> 16);  // RNE
}

// ---------------------------------------------------------------------------
// K1: txt fp32 -> bf16 B-frag order + img row hashes + zero acc/counter/rgc.
// 256 blocks x 256 threads (identical transform to R6, verified absmax 0.0).
// ---------------------------------------------------------------------------
__global__ __launch_bounds__(256) void prep_kernel(
        const float* __restrict__ img, const float* __restrict__ txt,
        u64* __restrict__ hashes, float* __restrict__ acc, int* __restrict__ counter,
        int* __restrict__ rgc, unsigned short* __restrict__ txtB) {
    if (blockIdx.x == 0) {
        if (threadIdx.x < 64) rgc[threadIdx.x] = 0;
        else if (threadIdx.x == 64) { *acc = 0.0f; *counter = 0; }
    }
    const int wave = threadIdx.x >> 6;
    const int lane = threadIdx.x & 63;

    for (int i = wave; i < 6; i += 4) {
        const int G  = blockIdx.x * 6 + i;
        const int tt = G / 24;        // col-tile 0..63
        const int g  = G - tt * 24;   // k-group 0..23
        const int col = tt * 16 + (lane & 15);
        const int k0  = g * 32 + (lane >> 4) * 8;
        const float4 va = *(const float4*)(txt + (size_t)col * DIM + k0);
        const float4 vb = *(const float4*)(txt + (size_t)col * DIM + k0 + 4);
        short8 hv = {(short)to_bf16(va.x), (short)to_bf16(va.y),
                     (short)to_bf16(va.z), (short)to_bf16(va.w),
                     (short)to_bf16(vb.x), (short)to_bf16(vb.y),
                     (short)to_bf16(vb.z), (short)to_bf16(vb.w)};
        *(short8*)(txtB + (size_t)(g * 64 + tt) * 512 + lane * 8) = hv;
    }

    // img row hash (order-independent positional hash; exact-verify later)
    const int row = blockIdx.x * 4 + wave;
    const float4* rp = (const float4*)(img + (size_t)row * DIM);
    u64 h = 0;
#pragma unroll
    for (int c = 0; c < 3; ++c) {
        float4 v = rp[c * 64 + lane];
        int p = c * 256 + lane * 4;
        h += ((u64)__float_as_uint(v.x) + 0x9E3779B97F4A7C15ULL) * (u64)(2 * p + 1);
        h += ((u64)__float_as_uint(v.y) + 0x9E3779B97F4A7C15ULL) * (u64)(2 * p + 3);
        h += ((u64)__float_as_uint(v.z) + 0x9E3779B97F4A7C15ULL) * (u64)(2 * p + 5);
        h += ((u64)__float_as_uint(v.w) + 0x9E3779B97F4A7C15ULL) * (u64)(2 * p + 7);
    }
#pragma unroll
    for (int m = 32; m; m >>= 1) h += __shfl_xor(h, m, 64);
    if (lane == 0) hashes[row] = h;
}

// ---------------------------------------------------------------------------
// K2: MFMA GEMM + softmax partials + fused finalize. 256 blocks x 1024 thr.
// Block = 16 rows x 256 cols (rg = b>>2, chunk = b&3). After writing its
// pmax/psum (release), block bumps rgc[rg] (acq_rel); the 4th arrival runs
// the final phase for its 16 rows: label scan + exact fp32 label dot + LSE
// combine -> atomicAdd(acc). 64th finalizer writes out. No spinning.
// ---------------------------------------------------------------------------
__global__ __launch_bounds__(1024) void gemm_final_kernel(
        const float* __restrict__ img, const float* __restrict__ txt,
        const float* __restrict__ scale_p, const u64* __restrict__ hashes,
        const unsigned short* __restrict__ txtB,
        float* __restrict__ pmax, float* __restrict__ psum,
        float* __restrict__ acc, int* __restrict__ counter, int* __restrict__ rgc,
        float* __restrict__ out) {
    __shared__ unsigned short Ahi[16 * DIM];   // 24 KB, A-frag order
    __shared__ float logitsS[16 * 260];        // 16.6 KB
    __shared__ int is_last_s;

    const int tid  = threadIdx.x;
    const int wave = tid >> 6;
    const int lane = tid & 63;
    const int quad = lane >> 4;
    const int l15  = lane & 15;
    const int rg    = blockIdx.x >> 2;
    const int chunk = blockIdx.x & 3;
    const int r0    = rg * 16;

    // stage A: wave w converts img row r0+w into frag order
    {
        const float* ir = img + (size_t)(r0 + wave) * DIM;
#pragma unroll
        for (int j = 0; j < 12; ++j) {
            const int k = lane + j * 64;
            Ahi[((k >> 3) * 16 + wave) * 8 + (k & 7)] = to_bf16(ir[k]);
        }
    }
    __syncthreads();

    // k-loop: wave's global col-tile t, one MFMA per 32-k step
    const int t = chunk * 16 + wave;
    const int foff = quad * 128 + l15 * 8;
    f32x4 a4 = {0.f, 0.f, 0.f, 0.f};
#pragma unroll
    for (int kk = 0; kk < 24; ++kk) {
        const short8 a = *(const short8*)&Ahi[kk * 512 + foff];
        const short8 b = *(const short8*)(txtB + (size_t)(kk * 64 + t) * 512 + foff);
        a4 = __builtin_amdgcn_mfma_f32_16x16x32_bf16(a, b, a4, 0, 0, 0);
    }

    // C layout: col = l15, row = quad*4 + r  [verified R3-R6, absmax 0.0]
    const float scale = scale_p[0];
#pragma unroll
    for (int r = 0; r < 4; ++r)
        logitsS[(quad * 4 + r) * 260 + wave * 16 + l15] = scale * a4[r];
    __syncthreads();

    // per-row partials: wave w = row w; 4 floats/lane over 256 cols
    {
        const float4 f = *(const float4*)&logitsS[wave * 260 + lane * 4];
        float mx = fmaxf(fmaxf(f.x, f.y), fmaxf(f.z, f.w));
#pragma unroll
        for (int s = 32; s; s >>= 1) mx = fmaxf(mx, __shfl_xor(mx, s, 64));
        float sum = __expf(f.x - mx) + __expf(f.y - mx) +
                    __expf(f.z - mx) + __expf(f.w - mx);
#pragma unroll
        for (int s = 32; s; s >>= 1) sum += __shfl_xor(sum, s, 64);
        if (lane == 0) {
            __hip_atomic_store(&pmax[(r0 + wave) * 4 + chunk], mx,
                               __ATOMIC_RELEASE, __HIP_MEMORY_SCOPE_AGENT);
            __hip_atomic_store(&psum[(r0 + wave) * 4 + chunk], sum,
                               __ATOMIC_RELEASE, __HIP_MEMORY_SCOPE_AGENT);
        }
    }
    __syncthreads();

    // arrival count for this row-group; 4th arrival finalizes
    if (tid == 0) {
        __threadfence();
        const int old = __hip_atomic_fetch_add(&rgc[rg], 1, __ATOMIC_ACQ_REL,
                                               __HIP_MEMORY_SCOPE_AGENT);
        is_last_s = (old == 3);
    }
    __syncthreads();
    if (!is_last_s) return;
    __threadfence();

    // ---- final phase: wave w owns row j = r0 + w ----
    const int j = r0 + wave;

    // duplicate label: first i<=j with img row i == row j (hash + verify)
    const u64 hj = hashes[j];
    int cand = BATCH;
    for (int i = lane; i < j; i += 64)
        if (hashes[i] == hj) { cand = i; break; }
    int label = j;
    for (;;) {
        int mm = cand;
#pragma unroll
        for (int s = 32; s; s >>= 1) mm = min(mm, __shfl_xor(mm, s, 64));
        if (mm >= j) break;
        const float4* rpm = (const float4*)(img + (size_t)mm * DIM);
        const float4* rpj = (const float4*)(img + (size_t)j * DIM);
        bool eq = true;
#pragma unroll
        for (int c = 0; c < 3; ++c) {
            float4 vm = rpm[c * 64 + lane];
            float4 vj = rpj[c * 64 + lane];
            eq = eq && (vm.x == vj.x) && (vm.y == vj.y) &&
                 (vm.z == vj.z) && (vm.w == vj.w);
        }
        if (__all(eq)) { label = mm; break; }
        if (cand == mm) {  // hash false positive: owning lane advances
            cand = BATCH;
            for (int i = mm + 64; i < j; i += 64)
                if (hashes[i] == hj) { cand = i; break; }
        }
    }

    // exact fp32 label logit: scale * dot(img[j], txt[label])
    const float4* aj = (const float4*)(img + (size_t)j * DIM);
    const float4* bl = (const float4*)(txt + (size_t)label * DIM);
    float s = 0.0f;
#pragma unroll
    for (int c = 0; c < 3; ++c) {
        const float4 va = aj[c * 64 + lane];
        const float4 vb = bl[c * 64 + lane];
        s += va.x * vb.x + va.y * vb.y + va.z * vb.z + va.w * vb.w;
    }
#pragma unroll
    for (int m = 32; m; m >>= 1) s += __shfl_xor(s, m, 64);

    if (lane == 0) {
        const float lval = scale_p[0] * s;
        const float m0 = __hip_atomic_load(&pmax[j*4+0], __ATOMIC_ACQUIRE, __HIP_MEMORY_SCOPE_AGENT);
        const float m1 = __hip_atomic_load(&pmax[j*4+1], __ATOMIC_ACQUIRE, __HIP_MEMORY_SCOPE_AGENT);
        const float m2 = __hip_atomic_load(&pmax[j*4+2], __ATOMIC_ACQUIRE, __HIP_MEMORY_SCOPE_AGENT);
        const float m3 = __hip_atomic_load(&pmax[j*4+3], __ATOMIC_ACQUIRE, __HIP_MEMORY_SCOPE_AGENT);
        const float s0 = __hip_atomic_load(&psum[j*4+0], __ATOMIC_ACQUIRE, __HIP_MEMORY_SCOPE_AGENT);
        const float s1 = __hip_atomic_load(&psum[j*4+1], __ATOMIC_ACQUIRE, __HIP_MEMORY_SCOPE_AGENT);
        const float s2 = __hip_atomic_load(&psum[j*4+2], __ATOMIC_ACQUIRE, __HIP_MEMORY_SCOPE_AGENT);
        const float s3 = __hip_atomic_load(&psum[j*4+3], __ATOMIC_ACQUIRE, __HIP_MEMORY_SCOPE_AGENT);
        const float gmax = fmaxf(fmaxf(m0, m1), fmaxf(m2, m3));
        const float ss = s0 * __expf(m0 - gmax) + s1 * __expf(m1 - gmax)
                       + s2 * __expf(m2 - gmax) + s3 * __expf(m3 - gmax);
        atomicAdd(acc, gmax + __logf(ss) - lval);  // row loss = lse - label_logit
    }
    __syncthreads();

    if (tid == 0) {
        __threadfence();
        const int old = __hip_atomic_fetch_add(counter, 1, __ATOMIC_ACQ_REL,
                                               __HIP_MEMORY_SCOPE_AGENT);
        if (old == 63) {
            __threadfence();
            out[0] = __hip_atomic_load(acc, __ATOMIC_ACQUIRE,
                                       __HIP_MEMORY_SCOPE_AGENT) * (1.0f / BATCH);
        }
    }
}

extern "C" void kernel_launch(void* const* d_in, const int* in_sizes, int n_in,
                              void* d_out, int out_size, void* d_ws, size_t ws_size,
                              hipStream_t stream) {
    const float* img   = (const float*)d_in[0];
    const float* txt   = (const float*)d_in[1];
    const float* scale = (const float*)d_in[2];
    float* out = (float*)d_out;
    char* ws = (char*)d_ws;

    u64*   hashes  = (u64*)ws;
    float* acc     = (float*)(ws + WS_ACC);
    int*   counter = (int*)(ws + WS_ACC + 4);
    int*   rgc     = (int*)(ws + WS_RGC);
    float* pmax    = (float*)(ws + WS_PMAX);
    float* psum    = (float*)(ws + WS_PSUM);
    unsigned short* txtB = (unsigned short*)(ws + WS_TXTB);

    prep_kernel<<<256, 256, 0, stream>>>(img, txt, hashes, acc, counter, rgc, txtB);
    gemm_final_kernel<<<256, 1024, 0, stream>>>(img, txt, scale, hashes, txtB,
                                                pmax, psum, acc, counter, rgc, out);
}

// Round 9
// 87.271 us; speedup vs baseline: 3.2841x; 3.2841x over previous
//
#include <hip/hip_runtime.h>
#include <stdint.h>

#define BATCH 1024
#define DIM 768

typedef unsigned long long u64;
typedef __attribute__((ext_vector_type(8))) short short8;  // 8 bf16 = 4 VGPRs
typedef __attribute__((ext_vector_type(4))) float f32x4;

// Workspace layout (bytes):
//   [0]      u64   hashes[1024]        (8 KB)
//   [8192]   float acc; int counter
//   [12288]  float pmax[1024*4]        per-row per-chunk max
//   [28672]  float psum[1024*4]        per-row per-chunk sumexp
//   [49152]  ushort txtB[1024*768]     (1.5 MB) bf16, MFMA B-frag order
// B-frag order: off(col,k) = ((k>>5)*64 + (col>>4))*512 + ((k>>3)&3)*128
//                            + (col&15)*8 + (k&7)
// -> a wave's 16x16x32 B-fragment is one contiguous 1 KB run (16 B/lane).
// Cross-XCD visibility: ONLY via kernel boundaries (R7 lesson: agent-scope
// acquire/release per-op L2 maintenance cost 3x the whole bench).
#define WS_ACC  8192
#define WS_PMAX 12288
#define WS_PSUM 28672
#define WS_TXTB 49152

__device__ __forceinline__ unsigned short to_bf16(float x) {
    unsigned int u = __float_as_uint(x);
    return (unsigned short)((u + 0x7FFFu + ((u >> 16) & 1u)) >> 16);  // RNE
}

// ---------------------------------------------------------------------------
// K1: txt fp32 -> bf16 B-frag order + img row hashes + zero acc/counter.
// 256 blocks x 256 threads (verified absmax 0.0 in R6).
// ---------------------------------------------------------------------------
__global__ __launch_bounds__(256) void prep_kernel(
        const float* __restrict__ img, const float* __restrict__ txt,
        u64* __restrict__ hashes, float* __restrict__ acc, int* __restrict__ counter,
        unsigned short* __restrict__ txtB) {
    if (blockIdx.x == 0 && threadIdx.x == 0) { *acc = 0.0f; *counter = 0; }
    const int wave = threadIdx.x >> 6;
    const int lane = threadIdx.x & 63;

    for (int i = wave; i < 6; i += 4) {
        const int G  = blockIdx.x * 6 + i;
        const int tt = G / 24;        // col-tile 0..63
        const int g  = G - tt * 24;   // k-group 0..23
        const int col = tt * 16 + (lane & 15);
        const int k0  = g * 32 + (lane >> 4) * 8;
        const float4 va = *(const float4*)(txt + (size_t)col * DIM + k0);
        const float4 vb = *(const float4*)(txt + (size_t)col * DIM + k0 + 4);
        short8 hv = {(short)to_bf16(va.x), (short)to_bf16(va.y),
                     (short)to_bf16(va.z), (short)to_bf16(va.w),
                     (short)to_bf16(vb.x), (short)to_bf16(vb.y),
                     (short)to_bf16(vb.z), (short)to_bf16(vb.w)};
        *(short8*)(txtB + (size_t)(g * 64 + tt) * 512 + lane * 8) = hv;
    }

    // img row hash (order-independent positional hash; exact-verify later)
    const int row = blockIdx.x * 4 + wave;
    const float4* rp = (const float4*)(img + (size_t)row * DIM);
    u64 h = 0;
#pragma unroll
    for (int c = 0; c < 3; ++c) {
        float4 v = rp[c * 64 + lane];
        int p = c * 256 + lane * 4;
        h += ((u64)__float_as_uint(v.x) + 0x9E3779B97F4A7C15ULL) * (u64)(2 * p + 1);
        h += ((u64)__float_as_uint(v.y) + 0x9E3779B97F4A7C15ULL) * (u64)(2 * p + 3);
        h += ((u64)__float_as_uint(v.z) + 0x9E3779B97F4A7C15ULL) * (u64)(2 * p + 5);
        h += ((u64)__float_as_uint(v.w) + 0x9E3779B97F4A7C15ULL) * (u64)(2 * p + 7);
    }
#pragma unroll
    for (int m = 32; m; m >>= 1) h += __shfl_xor(h, m, 64);
    if (lane == 0) hashes[row] = h;
}

// ---------------------------------------------------------------------------
// K2: MFMA GEMM + per-row per-chunk softmax partials. 256 blocks x 1024 thr.
// Block = 16 rows x 256 cols (rg = b>>2, chunk = b&3). Wave w owns col-tile
// chunk*16+w: 24 MFMAs. Partials computed from the C registers directly:
// quad-local butterfly over the wave's 16 cols, then 2 KB LDS combine across
// the 16 waves (replaces R6's 16.6 KB logits round-trip + extra barrier).
// ---------------------------------------------------------------------------
__global__ __launch_bounds__(1024) void gemm_kernel(
        const float* __restrict__ img, const float* __restrict__ scale_p,
        const unsigned short* __restrict__ txtB,
        float* __restrict__ pmax, float* __restrict__ psum) {
    __shared__ unsigned short Ahi[16 * DIM];   // 24 KB, A-frag order
    __shared__ float mxS[16 * 17];             // [row][wave], +1 pad
    __shared__ float smS[16 * 17];

    const int tid  = threadIdx.x;
    const int wave = tid >> 6;
    const int lane = tid & 63;
    const int quad = lane >> 4;
    const int l15  = lane & 15;
    const int r0    = (blockIdx.x >> 2) * 16;
    const int chunk = blockIdx.x & 3;

    // stage A: wave w converts img row r0+w into frag order
    {
        const float* ir = img + (size_t)(r0 + wave) * DIM;
#pragma unroll
        for (int j = 0; j < 12; ++j) {
            const int k = lane + j * 64;
            Ahi[((k >> 3) * 16 + wave) * 8 + (k & 7)] = to_bf16(ir[k]);
        }
    }
    __syncthreads();

    // k-loop: wave's global col-tile t, one MFMA per 32-k step
    const int t = chunk * 16 + wave;
    const int foff = quad * 128 + l15 * 8;
    f32x4 a4 = {0.f, 0.f, 0.f, 0.f};
#pragma unroll
    for (int kk = 0; kk < 24; ++kk) {
        const short8 a = *(const short8*)&Ahi[kk * 512 + foff];
        const short8 b = *(const short8*)(txtB + (size_t)(kk * 64 + t) * 512 + foff);
        a4 = __builtin_amdgcn_mfma_f32_16x16x32_bf16(a, b, a4, 0, 0, 0);
    }

    // C layout: col = l15, row = quad*4 + r  [verified R3-R6, absmax 0.0].
    // Per-(wave,row) partials over the wave's 16 cols: butterfly masks 1..8
    // stay within the 16-lane quad group.
    const float scale = scale_p[0];
#pragma unroll
    for (int r = 0; r < 4; ++r) {
        const float v = scale * a4[r];
        float mx = v;
#pragma unroll
        for (int m = 1; m <= 8; m <<= 1) mx = fmaxf(mx, __shfl_xor(mx, m, 64));
        float e = __expf(v - mx);
#pragma unroll
        for (int m = 1; m <= 8; m <<= 1) e += __shfl_xor(e, m, 64);
        if (l15 == 0) {
            mxS[(quad * 4 + r) * 17 + wave] = mx;
            smS[(quad * 4 + r) * 17 + wave] = e;
        }
    }
    __syncthreads();

    // wave w combines row w across the 16 waves (lanes 0..15 participate)
    {
        float mx = -INFINITY, e = 0.0f;
        if (lane < 16) { mx = mxS[wave * 17 + lane]; e = smS[wave * 17 + lane]; }
        float g = mx;
#pragma unroll
        for (int m = 1; m <= 8; m <<= 1) g = fmaxf(g, __shfl_xor(g, m, 64));
        e = (lane < 16) ? e * __expf(mx - g) : 0.0f;
#pragma unroll
        for (int m = 1; m <= 8; m <<= 1) e += __shfl_xor(e, m, 64);
        if (lane == 0) {
            pmax[(r0 + wave) * 4 + chunk] = g;
            psum[(r0 + wave) * 4 + chunk] = e;
        }
    }
}

// ---------------------------------------------------------------------------
// K3: labels + exact fp32 label-logit + chunk combine + mean. 64 blocks x
// 1024 threads; wave w owns row j = blockIdx*16 + w. Visibility of K2's
// plain stores comes from the kernel boundary (stream order).
// ---------------------------------------------------------------------------
__global__ __launch_bounds__(1024) void final_kernel(
        const float* __restrict__ img, const float* __restrict__ txt,
        const float* __restrict__ scale_p, const u64* __restrict__ hashes,
        const float* __restrict__ pmax, const float* __restrict__ psum,
        float* __restrict__ acc, int* __restrict__ counter,
        float* __restrict__ out) {
    const int tid  = threadIdx.x;
    const int wave = tid >> 6;
    const int lane = tid & 63;
    const int j = blockIdx.x * 16 + wave;

    // duplicate label: first i<=j with img row i == row j (hash + verify)
    const u64 hj = hashes[j];
    int cand = BATCH;
    for (int i = lane; i < j; i += 64)
        if (hashes[i] == hj) { cand = i; break; }
    int label = j;
    for (;;) {
        int mm = cand;
#pragma unroll
        for (int s = 32; s; s >>= 1) mm = min(mm, __shfl_xor(mm, s, 64));
        if (mm >= j) break;
        const float4* rpm = (const float4*)(img + (size_t)mm * DIM);
        const float4* rpj = (const float4*)(img + (size_t)j * DIM);
        bool eq = true;
#pragma unroll
        for (int c = 0; c < 3; ++c) {
            float4 vm = rpm[c * 64 + lane];
            float4 vj = rpj[c * 64 + lane];
            eq = eq && (vm.x == vj.x) && (vm.y == vj.y) &&
                 (vm.z == vj.z) && (vm.w == vj.w);
        }
        if (__all(eq)) { label = mm; break; }
        if (cand == mm) {  // hash false positive: owning lane advances
            cand = BATCH;
            for (int i = mm + 64; i < j; i += 64)
                if (hashes[i] == hj) { cand = i; break; }
        }
    }

    // exact fp32 label logit: scale * dot(img[j], txt[label])
    const float4* aj = (const float4*)(img + (size_t)j * DIM);
    const float4* bl = (const float4*)(txt + (size_t)label * DIM);
    float s = 0.0f;
#pragma unroll
    for (int c = 0; c < 3; ++c) {
        const float4 va = aj[c * 64 + lane];
        const float4 vb = bl[c * 64 + lane];
        s += va.x * vb.x + va.y * vb.y + va.z * vb.z + va.w * vb.w;
    }
#pragma unroll
    for (int m = 32; m; m >>= 1) s += __shfl_xor(s, m, 64);

    if (lane == 0) {
        const float lval = scale_p[0] * s;
        const float m0 = pmax[j * 4 + 0], m1 = pmax[j * 4 + 1];
        const float m2 = pmax[j * 4 + 2], m3 = pmax[j * 4 + 3];
        const float gmax = fmaxf(fmaxf(m0, m1), fmaxf(m2, m3));
        const float ss = psum[j * 4 + 0] * __expf(m0 - gmax)
                       + psum[j * 4 + 1] * __expf(m1 - gmax)
                       + psum[j * 4 + 2] * __expf(m2 - gmax)
                       + psum[j * 4 + 3] * __expf(m3 - gmax);
        const float lse = gmax + __logf(ss);
        atomicAdd(acc, lse - lval);   // row loss = lse - label_logit
    }
    __syncthreads();

    if (tid == 0) {
        __threadfence();
        const int old = atomicAdd(counter, 1);
        if (old == (int)gridDim.x - 1) {
            __threadfence();
            out[0] = (*(volatile float*)acc) * (1.0f / BATCH);
        }
    }
}

extern "C" void kernel_launch(void* const* d_in, const int* in_sizes, int n_in,
                              void* d_out, int out_size, void* d_ws, size_t ws_size,
                              hipStream_t stream) {
    const float* img   = (const float*)d_in[0];
    const float* txt   = (const float*)d_in[1];
    const float* scale = (const float*)d_in[2];
    float* out = (float*)d_out;
    char* ws = (char*)d_ws;

    u64*   hashes  = (u64*)ws;
    float* acc     = (float*)(ws + WS_ACC);
    int*   counter = (int*)(ws + WS_ACC + 4);
    float* pmax    = (float*)(ws + WS_PMAX);
    float* psum    = (float*)(ws + WS_PSUM);
    unsigned short* txtB = (unsigned short*)(ws + WS_TXTB);

    prep_kernel<<<256, 256, 0, stream>>>(img, txt, hashes, acc, counter, txtB);
    gemm_kernel<<<256, 1024, 0, stream>>>(img, scale, txtB, pmax, psum);
    final_kernel<<<64, 1024, 0, stream>>>(img, txt, scale, hashes, pmax, psum,
                                          acc, counter, out);
}